// Round 7
// baseline (254.149 us; speedup 1.0000x reference)
//
#include <hip/hip_runtime.h>

typedef unsigned short u16;
typedef unsigned int u32;
typedef unsigned char u8;
typedef __attribute__((ext_vector_type(4))) int int4v;
typedef __attribute__((ext_vector_type(8))) int int8v;
typedef __attribute__((ext_vector_type(4))) float f32x4;

#define NEG (-1e30f)
#define LN2 0.6931471805599453f
#define INV_LN2 1.4426950408889634f

// Problem sizes
#define B_N 16
#define T_N 500
#define E_N 1024
#define V_N 4000
#define L_N 100
#define M_P 8064     // 63*128 padded rows
#define N_P 4096     // 32*128 padded vocab
#define LLW 104      // lab row stride in bf16 elems (208 B, 16B-aligned)

// ws layout (bytes)
#define OFF_A   0UL          // fp8 A  [8064][1024]  = 8,257,536
#define OFF_B   8257536UL    // fp8 Bt [4096][1024]  = 4,194,304
#define OFF_C   12451840UL   // bf16 C [8064][4096]  = 66,060,288
#define OFF_LAB 78512128UL   // bf16 lab[8000][104]  = 1,664,000 (+1 KB DMA slack)

__device__ __forceinline__ u16 f2bf(float f) {
  u32 u = __float_as_uint(f);
  u += 0x7fffu + ((u >> 16) & 1u);   // RNE
  return (u16)(u >> 16);
}
__device__ __forceinline__ float bf2f(u16 h) {
  return __uint_as_float(((u32)h) << 16);
}
__device__ __forceinline__ float lse2_2(float x, float y) {
  float m = fmaxf(x, y);
  float d = -fabsf(x - y);
  return m + __log2f(1.0f + exp2f(d));
}
__device__ __forceinline__ float lse3_2(float x, float y, float z) {
  float m = fmaxf(fmaxf(x, y), z);
  return m + __log2f(exp2f(x - m) + exp2f(y - m) + exp2f(z - m));
}
__device__ __forceinline__ void gl_lds16(const void* g, void* l) {
  __builtin_amdgcn_global_load_lds((const __attribute__((address_space(1))) void*)g,
                                   (__attribute__((address_space(3))) void*)l, 16, 0, 0);
}
// lane L <- lane L-1 via DPP WF_SHR1 (pure VALU); lane 0 takes `fill`.
__device__ __forceinline__ float dpp_shr1(float x, float fill) {
  int r = __builtin_amdgcn_update_dpp(__float_as_int(fill), __float_as_int(x),
                                      0x138, 0xF, 0xF, false);
  return __int_as_float(r);
}

// K1: cast hs [8000][1024] f32 -> fp8 e4m3 A [8064][1024] (pad rows 0); zero d_out
__global__ __launch_bounds__(256) void castA(const float* __restrict__ hs,
                                             u32* __restrict__ Aq,
                                             float* __restrict__ out) {
  int idx = blockIdx.x * 256 + threadIdx.x;   // 4 elems per thread
  if (idx == 0) out[0] = 0.f;
  int row = idx >> 8;
  float4 x;
  if (row < B_N * T_N) x = ((const float4*)hs)[idx];
  else x = make_float4(0.f, 0.f, 0.f, 0.f);
  u32 p = __builtin_amdgcn_cvt_pk_fp8_f32(x.x, x.y, 0, false);
  p = __builtin_amdgcn_cvt_pk_fp8_f32(x.z, x.w, p, true);
  Aq[idx] = p;
}

// K2: transpose-cast W [1024][4000] f32 -> fp8 Bt [4096][1024], scaled x64
__global__ __launch_bounds__(256) void castB(const float* __restrict__ W,
                                             u8* __restrict__ Bq) {
  __shared__ float tile[32][33];
  int v0 = blockIdx.x * 32;   // vocab
  int e0 = blockIdx.y * 32;   // embed
  int tx = threadIdx.x & 31, ty = threadIdx.x >> 5;  // 32 x 8
#pragma unroll
  for (int i = 0; i < 4; ++i) {
    int e = e0 + ty * 4 + i;
    int v = v0 + tx;
    tile[ty * 4 + i][tx] = (v < V_N) ? W[e * V_N + v] : 0.f;
  }
  __syncthreads();
#pragma unroll
  for (int i = 0; i < 4; ++i) {
    int vloc = ty * 4 + i;
    float x = tile[tx][vloc] * 64.f;   // exact pow2 pre-scale into e4m3 range
    u32 p = __builtin_amdgcn_cvt_pk_fp8_f32(x, x, 0, false);
    Bq[(size_t)(v0 + vloc) * 1024 + (e0 + tx)] = (u8)(p & 0xff);
  }
}

// K3: 128x128x128 K-tile MX-fp8 MFMA GEMM (scales=2^0 -> plain fp8 at 2x rate).
__global__ __launch_bounds__(256, 2) void gemm_fp8(const u8* __restrict__ A,
                                                   const u8* __restrict__ Bq,
                                                   u16* __restrict__ C) {
  __shared__ __align__(16) u8 As[16 * 1056];
  __shared__ __align__(16) u8 Bs[16 * 1056];
  const int tid = threadIdx.x;
  const int lane = tid & 63;
  const int w = tid >> 6;          // wave 0..3
  const int wm = w >> 1, wn = w & 1;
  const size_t m0 = (size_t)blockIdx.y * 128;
  const size_t n0 = (size_t)blockIdx.x * 128;

  const int lr = lane >> 3;        // row in 8-row group
  const int lc = lane & 7;         // LDS slot
  const int gc = lc ^ lr;          // global chunk this lane fetches
  const u8* gA = A + (m0 + w * 32 + lr) * 1024 + gc * 16;
  const u8* gB = Bq + (n0 + w * 32 + lr) * 1024 + gc * 16;
  u8* sA = As + (w * 4) * 1056;
  u8* sB = Bs + (w * 4) * 1056;

  f32x4 acc[4][4];
#pragma unroll
  for (int i = 0; i < 4; ++i)
#pragma unroll
    for (int j = 0; j < 4; ++j) acc[i][j] = (f32x4){0.f, 0.f, 0.f, 0.f};

  const int fr = lane & 15, q = lane >> 4;
  const int c0 = ((2 * q) ^ (fr & 7)) * 16;       // swizzled chunk addrs
  const int c1 = ((2 * q + 1) ^ (fr & 7)) * 16;
  const int rA0 = wm * 64 + fr;
  const int rB0 = wn * 64 + fr;

  for (int kt = 0; kt < 1024; kt += 128) {
#pragma unroll
    for (int u = 0; u < 4; ++u) {
      gl_lds16(gA + (size_t)u * 8192 + kt, sA + u * 1056);
      gl_lds16(gB + (size_t)u * 8192 + kt, sB + u * 1056);
    }
    __syncthreads();
    int8v af[4], bf[4];
#pragma unroll
    for (int i = 0; i < 4; ++i) {
      int r = rA0 + i * 16;
      const u8* p = As + (r >> 3) * 1056 + (r & 7) * 128;
      int4v lo = *(const int4v*)(p + c0);
      int4v hi = *(const int4v*)(p + c1);
      af[i] = (int8v){lo[0], lo[1], lo[2], lo[3], hi[0], hi[1], hi[2], hi[3]};
    }
#pragma unroll
    for (int j = 0; j < 4; ++j) {
      int r = rB0 + j * 16;
      const u8* p = Bs + (r >> 3) * 1056 + (r & 7) * 128;
      int4v lo = *(const int4v*)(p + c0);
      int4v hi = *(const int4v*)(p + c1);
      bf[j] = (int8v){lo[0], lo[1], lo[2], lo[3], hi[0], hi[1], hi[2], hi[3]};
    }
#pragma unroll
    for (int i = 0; i < 4; ++i)
#pragma unroll
      for (int j = 0; j < 4; ++j)
        acc[i][j] = __builtin_amdgcn_mfma_scale_f32_16x16x128_f8f6f4(
            af[i], bf[j], acc[i][j], 0, 0,        // cbsz=fp8, blgp=fp8
            0, 0x7F7F7F7F, 0, 0x7F7F7F7F);        // E8M0 127 = 2^0
    __syncthreads();
  }

  // C/D: col=lane&15, row=(lane>>4)*4+reg; undo W x64 pre-scale
  const int cq = lane >> 4, cc = lane & 15;
#pragma unroll
  for (int i = 0; i < 4; ++i)
#pragma unroll
    for (int j = 0; j < 4; ++j) {
      size_t rr = m0 + wm * 64 + i * 16 + cq * 4;
      size_t nn = n0 + wn * 64 + j * 16 + cc;
      u16* o = C + rr * N_P + nn;
#pragma unroll
      for (int g = 0; g < 4; ++g) o[(size_t)g * N_P] = f2bf(acc[i][j][g] * 0.015625f);
    }
}

// K4: per-row logsumexp over V + gather label log-probs -> bf16 lab [8000][104]
// (log2 domain; bf16 rounding adds ~0.5 random-walk error on a ~3000 loss)
__global__ __launch_bounds__(256) void rowstat(const u16* __restrict__ C,
                                               const float* __restrict__ bias,
                                               const int* __restrict__ ys,
                                               u16* __restrict__ lab) {
  int r = blockIdx.x;
  int tid = threadIdx.x;
  const u16* row = C + (size_t)r * N_P;
  float v[16];
  float mx = NEG;
#pragma unroll
  for (int u = 0; u < 16; ++u) {
    int c = tid + (u << 8);
    float x = (c < V_N) ? bf2f(row[c]) + bias[c] : NEG;
    v[u] = x;
    mx = fmaxf(mx, x);
  }
#pragma unroll
  for (int o = 32; o > 0; o >>= 1) mx = fmaxf(mx, __shfl_xor(mx, o));
  __shared__ float sm[4], ss[4];
  int w = tid >> 6;
  if ((tid & 63) == 0) sm[w] = mx;
  __syncthreads();
  mx = fmaxf(fmaxf(sm[0], sm[1]), fmaxf(sm[2], sm[3]));
  float s = 0.f;
#pragma unroll
  for (int u = 0; u < 16; ++u) s += __expf(v[u] - mx);
#pragma unroll
  for (int o = 32; o > 0; o >>= 1) s += __shfl_xor(s, o);
  if ((tid & 63) == 0) ss[w] = s;
  __syncthreads();
  float lse = mx + __logf(ss[0] + ss[1] + ss[2] + ss[3]);
  if (tid < 1 + L_N) {
    int b = r / T_N;
    int lab_id = (tid == 0) ? 0 : max(ys[b * L_N + tid - 1], 0);
    lab[(size_t)r * LLW + tid] = f2bf((bf2f(row[lab_id]) + bias[lab_id] - lse) * INV_LN2);
  }
}

// K5: CTC DP, log2 domain, blocked states, DPP wave-shift. The ENTIRE batch
// lab table (500 x 104 bf16 = 104 KB) is DMA'd into LDS up front with ONE
// vmcnt(0) wait; the 499-step loop is then pure LDS-read + VALU (no vmcnt,
// compiler-managed lgkmcnt only). Single wave per block: no barriers.
__global__ __launch_bounds__(64) void ctc_dp(const u16* __restrict__ lab,
                                             const int* __restrict__ ys,
                                             const int* __restrict__ ilens,
                                             const int* __restrict__ olens,
                                             float* __restrict__ out) {
  __shared__ __align__(16) u16 lb[102 * 512];   // 104,448 B (covers 500*104 + slack)
  int b = blockIdx.x;
  int L = threadIdx.x;
  const char* gb = (const char*)(lab + (size_t)b * T_N * LLW);

  // stage whole batch: 102 chunks x 1 KB (lane L covers 16 B at +L*16)
#pragma unroll 6
  for (int i = 0; i < 102; ++i)
    gl_lds16(gb + i * 1024 + L * 16, ((char*)lb) + i * 1024);

  int k0 = 2 * L, k1 = 2 * L + 1;
  int k0c = min(k0, L_N - 1), k1c = min(k1, L_N - 1);
  int y0 = max(ys[b * L_N + k0c], 0);
  int y1 = max(ys[b * L_N + k1c], 0);
  int y0m = (k0 > 0) ? max(ys[b * L_N + min(k0 - 1, L_N - 1)], 0) : -1;
  bool allow1 = (y0 != 0) && (y0 != y0m);
  bool allow3 = (y1 != 0) && (y1 != y0);
  int slotK0 = 1 + k0c, slotK1 = 1 + k1c;
  int il = ilens[b];   // >= 250

  asm volatile("s_waitcnt vmcnt(0)" ::: "memory");   // all DMA landed

  float a0 = (L == 0) ? bf2f(lb[0]) : NEG;
  float a1 = (L == 0) ? bf2f(lb[1]) : NEG;
  float a2 = NEG, a3 = NEG;

  for (int t0 = 1; t0 < il; t0 += 8) {
    const u16* bp = lb + (size_t)t0 * LLW;
    float rB[8], rK0[8], rK1[8];
#pragma unroll
    for (int u = 0; u < 8; ++u) {
      rB[u] = bf2f(bp[u * LLW]);
      rK0[u] = bf2f(bp[u * LLW + slotK0]);
      rK1[u] = bf2f(bp[u * LLW + slotK1]);
    }
#pragma unroll
    for (int u = 0; u < 8; ++u) {
      int t = t0 + u;
      float p3 = dpp_shr1(a3, NEG);           // lane L <- a3 of lane L-1
      float p3m = allow1 ? p3 : NEG;
      float a1m = allow3 ? a1 : NEG;
      float n0 = lse2_2(a0, p3) + rB[u];
      float n1 = lse3_2(a1, a0, p3m) + rK0[u];
      float n2 = lse2_2(a2, a1) + rB[u];
      float n3 = lse3_2(a3, a2, a1m) + rK1[u];
      bool live = t < il;   // wave-uniform freeze (garbage rows masked here)
      a0 = live ? n0 : a0; a1 = live ? n1 : a1;
      a2 = live ? n2 : a2; a3 = live ? n3 : a3;
    }
  }

  int ol = olens[b];
  int s1 = 2 * ol, s2 = 2 * ol - 1;
  int j1 = s1 & 3, j2 = s2 & 3;
  float t1 = (j1 == 0) ? a0 : a2;
  float t2 = (j2 == 1) ? a1 : a3;
  float x1 = __shfl(t1, s1 >> 2);
  float x2 = __shfl(t2, s2 >> 2);
  float ll = lse2_2(x1, x2) * LN2;
  if (L == 0) atomicAdd(out, -ll * (1.0f / B_N));
}

extern "C" void kernel_launch(void* const* d_in, const int* in_sizes, int n_in,
                              void* d_out, int out_size, void* d_ws, size_t ws_size,
                              hipStream_t stream) {
  const float* hs    = (const float*)d_in[0];
  const float* W     = (const float*)d_in[1];
  const float* bias  = (const float*)d_in[2];
  const int*   ys    = (const int*)d_in[3];
  const int*   ilens = (const int*)d_in[4];
  const int*   olens = (const int*)d_in[5];
  char* ws = (char*)d_ws;
  u8*    Aq  = (u8*)(ws + OFF_A);
  u8*    Bq  = (u8*)(ws + OFF_B);
  u16*   C   = (u16*)(ws + OFF_C);
  u16*   lab = (u16*)(ws + OFF_LAB);
  float* out = (float*)d_out;

  castA<<<M_P * E_N / (256 * 4), 256, 0, stream>>>(hs, (u32*)Aq, out);
  castB<<<dim3(N_P / 32, E_N / 32), 256, 0, stream>>>(W, Bq);
  gemm_fp8<<<dim3(N_P / 128, M_P / 128), 256, 0, stream>>>(Aq, Bq, C);
  rowstat<<<B_N * T_N, 256, 0, stream>>>(C, bias, ys, lab);
  ctc_dp<<<B_N, 64, 0, stream>>>(lab, ys, ilens, olens, out);
}

// Round 9
// 192.562 us; speedup vs baseline: 1.3198x; 1.3198x over previous
//
#include <hip/hip_runtime.h>

typedef unsigned short u16;
typedef unsigned int u32;
typedef unsigned char u8;
typedef __attribute__((ext_vector_type(4))) int int4v;
typedef __attribute__((ext_vector_type(8))) int int8v;
typedef __attribute__((ext_vector_type(4))) float f32x4;

#define NEG (-1e30f)
#define LN2 0.6931471805599453f
#define INV_LN2 1.4426950408889634f

// Problem sizes
#define B_N 16
#define T_N 500
#define E_N 1024
#define V_N 4000
#define L_N 100
#define M_P 8064     // 63*128 padded rows
#define N_P 4096     // 32*128 padded vocab

// lab region layout (per batch): pairs u32[500][64] = 128000 B,
// PB f32[500] (pad 2048 B), cT f32[500] (pad 2048 B)
#define PAIRS_B 128000UL
#define PB_OFF  128000UL
#define CT_OFF  130048UL
#define BSTRIDE 132096UL

// ws layout (bytes)
#define OFF_A   0UL          // fp8 A  [8064][1024]  = 8,257,536
#define OFF_B   8257536UL    // fp8 Bt [4096][1024]  = 4,194,304
#define OFF_C   12451840UL   // bf16 C [8064][4096]  = 66,060,288
#define OFF_LAB 78512128UL   // 16 * 132096 = 2,113,536 (end ~80.6 MB)

__device__ __forceinline__ u16 f2bf(float f) {
  u32 u = __float_as_uint(f);
  u += 0x7fffu + ((u >> 16) & 1u);   // RNE
  return (u16)(u >> 16);
}
__device__ __forceinline__ float bf2f(u16 h) {
  return __uint_as_float(((u32)h) << 16);
}
__device__ __forceinline__ void gl_lds16(const void* g, void* l) {
  __builtin_amdgcn_global_load_lds((const __attribute__((address_space(1))) void*)g,
                                   (__attribute__((address_space(3))) void*)l, 16, 0, 0);
}
// DPP helpers: ctrl must be an ICE -> template parameter.
template <int CTRL>
__device__ __forceinline__ float dpp_f(float x, float fill) {
  return __int_as_float(__builtin_amdgcn_update_dpp(
      __float_as_int(fill), __float_as_int(x), CTRL, 0xF, 0xF, false));
}
// lane L <- lane L-1 (wf_shr1); lane 0 takes fill.
__device__ __forceinline__ float dpp_shr1(float x, float fill) {
  return dpp_f<0x138>(x, fill);
}
// wave max -> result valid in lane 63. fill must be the identity.
__device__ __forceinline__ float wave_max(float x, float fill) {
  x = fmaxf(x, dpp_f<0x111>(x, fill));   // row_shr:1
  x = fmaxf(x, dpp_f<0x112>(x, fill));   // row_shr:2
  x = fmaxf(x, dpp_f<0x114>(x, fill));   // row_shr:4
  x = fmaxf(x, dpp_f<0x118>(x, fill));   // row_shr:8
  x = fmaxf(x, dpp_f<0x142>(x, fill));   // row_bcast:15
  x = fmaxf(x, dpp_f<0x143>(x, fill));   // row_bcast:31
  return x;
}
// wave sum -> result valid in lane 63.
__device__ __forceinline__ float wave_sum(float x) {
  x += dpp_f<0x111>(x, 0.f); x += dpp_f<0x112>(x, 0.f);
  x += dpp_f<0x114>(x, 0.f); x += dpp_f<0x118>(x, 0.f);
  x += dpp_f<0x142>(x, 0.f); x += dpp_f<0x143>(x, 0.f);
  return x;
}

// K1: cast hs [8000][1024] f32 -> fp8 e4m3 A [8064][1024] (pad rows 0); zero d_out
__global__ __launch_bounds__(256) void castA(const float* __restrict__ hs,
                                             u32* __restrict__ Aq,
                                             float* __restrict__ out) {
  int idx = blockIdx.x * 256 + threadIdx.x;   // 4 elems per thread
  if (idx == 0) out[0] = 0.f;
  int row = idx >> 8;
  float4 x;
  if (row < B_N * T_N) x = ((const float4*)hs)[idx];
  else x = make_float4(0.f, 0.f, 0.f, 0.f);
  u32 p = __builtin_amdgcn_cvt_pk_fp8_f32(x.x, x.y, 0, false);
  p = __builtin_amdgcn_cvt_pk_fp8_f32(x.z, x.w, p, true);
  Aq[idx] = p;
}

// K2: transpose-cast W [1024][4000] f32 -> fp8 Bt [4096][1024], scaled x64
__global__ __launch_bounds__(256) void castB(const float* __restrict__ W,
                                             u8* __restrict__ Bq) {
  __shared__ float tile[32][33];
  int v0 = blockIdx.x * 32;   // vocab
  int e0 = blockIdx.y * 32;   // embed
  int tx = threadIdx.x & 31, ty = threadIdx.x >> 5;  // 32 x 8
#pragma unroll
  for (int i = 0; i < 4; ++i) {
    int e = e0 + ty * 4 + i;
    int v = v0 + tx;
    tile[ty * 4 + i][tx] = (v < V_N) ? W[e * V_N + v] : 0.f;
  }
  __syncthreads();
#pragma unroll
  for (int i = 0; i < 4; ++i) {
    int vloc = ty * 4 + i;
    float x = tile[tx][vloc] * 64.f;   // exact pow2 pre-scale into e4m3 range
    u32 p = __builtin_amdgcn_cvt_pk_fp8_f32(x, x, 0, false);
    Bq[(size_t)(v0 + vloc) * 1024 + (e0 + tx)] = (u8)(p & 0xff);
  }
}

// K3: 128x128x128 K-tile MX-fp8 MFMA GEMM (scales=2^0 -> plain fp8 at 2x rate).
__global__ __launch_bounds__(256, 2) void gemm_fp8(const u8* __restrict__ A,
                                                   const u8* __restrict__ Bq,
                                                   u16* __restrict__ C) {
  __shared__ __align__(16) u8 As[16 * 1056];
  __shared__ __align__(16) u8 Bs[16 * 1056];
  const int tid = threadIdx.x;
  const int lane = tid & 63;
  const int w = tid >> 6;          // wave 0..3
  const int wm = w >> 1, wn = w & 1;
  const size_t m0 = (size_t)blockIdx.y * 128;
  const size_t n0 = (size_t)blockIdx.x * 128;

  const int lr = lane >> 3;        // row in 8-row group
  const int lc = lane & 7;         // LDS slot
  const int gc = lc ^ lr;          // global chunk this lane fetches
  const u8* gA = A + (m0 + w * 32 + lr) * 1024 + gc * 16;
  const u8* gB = Bq + (n0 + w * 32 + lr) * 1024 + gc * 16;
  u8* sA = As + (w * 4) * 1056;
  u8* sB = Bs + (w * 4) * 1056;

  f32x4 acc[4][4];
#pragma unroll
  for (int i = 0; i < 4; ++i)
#pragma unroll
    for (int j = 0; j < 4; ++j) acc[i][j] = (f32x4){0.f, 0.f, 0.f, 0.f};

  const int fr = lane & 15, q = lane >> 4;
  const int c0 = ((2 * q) ^ (fr & 7)) * 16;       // swizzled chunk addrs
  const int c1 = ((2 * q + 1) ^ (fr & 7)) * 16;
  const int rA0 = wm * 64 + fr;
  const int rB0 = wn * 64 + fr;

  for (int kt = 0; kt < 1024; kt += 128) {
#pragma unroll
    for (int u = 0; u < 4; ++u) {
      gl_lds16(gA + (size_t)u * 8192 + kt, sA + u * 1056);
      gl_lds16(gB + (size_t)u * 8192 + kt, sB + u * 1056);
    }
    __syncthreads();
    int8v af[4], bf[4];
#pragma unroll
    for (int i = 0; i < 4; ++i) {
      int r = rA0 + i * 16;
      const u8* p = As + (r >> 3) * 1056 + (r & 7) * 128;
      int4v lo = *(const int4v*)(p + c0);
      int4v hi = *(const int4v*)(p + c1);
      af[i] = (int8v){lo[0], lo[1], lo[2], lo[3], hi[0], hi[1], hi[2], hi[3]};
    }
#pragma unroll
    for (int j = 0; j < 4; ++j) {
      int r = rB0 + j * 16;
      const u8* p = Bs + (r >> 3) * 1056 + (r & 7) * 128;
      int4v lo = *(const int4v*)(p + c0);
      int4v hi = *(const int4v*)(p + c1);
      bf[j] = (int8v){lo[0], lo[1], lo[2], lo[3], hi[0], hi[1], hi[2], hi[3]};
    }
#pragma unroll
    for (int i = 0; i < 4; ++i)
#pragma unroll
      for (int j = 0; j < 4; ++j)
        acc[i][j] = __builtin_amdgcn_mfma_scale_f32_16x16x128_f8f6f4(
            af[i], bf[j], acc[i][j], 0, 0,        // cbsz=fp8, blgp=fp8
            0, 0x7F7F7F7F, 0, 0x7F7F7F7F);        // E8M0 127 = 2^0
    __syncthreads();
  }

  // C/D: col=lane&15, row=(lane>>4)*4+reg; undo W x64 pre-scale
  const int cq = lane >> 4, cc = lane & 15;
#pragma unroll
  for (int i = 0; i < 4; ++i)
#pragma unroll
    for (int j = 0; j < 4; ++j) {
      size_t rr = m0 + wm * 64 + i * 16 + cq * 4;
      size_t nn = n0 + wn * 64 + j * 16 + cc;
      u16* o = C + rr * N_P + nn;
#pragma unroll
      for (int g = 0; g < 4; ++g) o[(size_t)g * N_P] = f2bf(acc[i][j][g] * 0.015625f);
    }
}

// K4: per-row logsumexp over V, then row-max-normalized LINEAR probabilities:
// c_t = max over 101 slots of lp2; pairs[t][L] = bf16(2^(lp2[1+2L]-c), 2^(lp2[2+2L]-c));
// PB[t] = 2^(lp2[0]-c) f32; cT[t] = c f32.
__global__ __launch_bounds__(256) void rowstat(const u16* __restrict__ C,
                                               const float* __restrict__ bias,
                                               const int* __restrict__ ys,
                                               u8* __restrict__ labbase) {
  int r = blockIdx.x;
  int tid = threadIdx.x;
  const u16* row = C + (size_t)r * N_P;
  int b = r / T_N;
  int t = r - b * T_N;
  float v[16];
  float mx = NEG;
#pragma unroll
  for (int u = 0; u < 16; ++u) {
    int c = tid + (u << 8);
    float x = (c < V_N) ? bf2f(row[c]) + bias[c] : NEG;
    v[u] = x;
    mx = fmaxf(mx, x);
  }
#pragma unroll
  for (int o = 32; o > 0; o >>= 1) mx = fmaxf(mx, __shfl_xor(mx, o));
  __shared__ float sm[4], ss[4];
  __shared__ float arr[104];
  __shared__ float cbr;
  int w = tid >> 6;
  if ((tid & 63) == 0) sm[w] = mx;
  __syncthreads();
  mx = fmaxf(fmaxf(sm[0], sm[1]), fmaxf(sm[2], sm[3]));
  float s = 0.f;
#pragma unroll
  for (int u = 0; u < 16; ++u) s += __expf(v[u] - mx);
#pragma unroll
  for (int o = 32; o > 0; o >>= 1) s += __shfl_xor(s, o);
  if ((tid & 63) == 0) ss[w] = s;
  __syncthreads();
  float lse = mx + __logf(ss[0] + ss[1] + ss[2] + ss[3]);

  if (tid <= 100) {
    int lab_id = (tid == 0) ? 0 : max(ys[b * L_N + tid - 1], 0);
    arr[tid] = (bf2f(row[lab_id]) + bias[lab_id] - lse) * INV_LN2;
  } else if (tid <= 103) {
    arr[tid] = NEG;
  }
  __syncthreads();
  if (tid < 64) {
    float vv = fmaxf(arr[tid], (tid < 40) ? arr[tid + 64] : NEG);
    vv = wave_max(vv, NEG);     // NEG fill: values are negative
    if (tid == 63) cbr = vv;
  }
  __syncthreads();
  float c = cbr;

  u8* base = labbase + (size_t)b * BSTRIDE;
  if (tid < 64) {
    float p0 = (tid < 50) ? exp2f(arr[1 + 2 * tid] - c) : 0.f;
    float p1 = (tid < 50) ? exp2f(arr[2 + 2 * tid] - c) : 0.f;
    u32 pk = ((u32)f2bf(p1) << 16) | (u32)f2bf(p0);
    ((u32*)base)[(size_t)t * 64 + tid] = pk;
  } else if (tid == 64) {
    ((float*)(base + PB_OFF))[t] = exp2f(arr[0] - c);
    ((float*)(base + CT_OFF))[t] = c;
  }
}

// K5: CTC forward DP in LINEAR domain (scaled forward algorithm).
// No transcendentals in the loop: n = (self + prev [+ skip]) * P'.
// Per-8-step renorm: wave-max via DPP, exact pow2 scale from exponent bits,
// integer exponent accumulator. Sum of c_t reclaimed at the end.
__global__ __launch_bounds__(64) void ctc_dp(const u8* __restrict__ labbase,
                                             const int* __restrict__ ys,
                                             const int* __restrict__ ilens,
                                             const int* __restrict__ olens,
                                             float* __restrict__ out) {
  __shared__ __align__(16) u8 sP[128000];    // pairs u32[500][64]
  __shared__ __align__(16) u8 sPBb[2048];    // PB f32[500]
  __shared__ __align__(16) u8 sCTb[2048];    // cT f32[500]
  int b = blockIdx.x;
  int L = threadIdx.x;
  const u8* gb = labbase + (size_t)b * BSTRIDE;

  // stage: 125 + 2 + 2 chunks of 1 KB (lane L covers 16 B at +L*16)
#pragma unroll 5
  for (int i = 0; i < 125; ++i)
    gl_lds16(gb + (size_t)i * 1024 + L * 16, sP + i * 1024);
  gl_lds16(gb + PB_OFF + L * 16, sPBb);
  gl_lds16(gb + PB_OFF + 1024 + L * 16, sPBb + 1024);
  gl_lds16(gb + CT_OFF + L * 16, sCTb);
  gl_lds16(gb + CT_OFF + 1024 + L * 16, sCTb + 1024);

  // transition masks (lane L holds states 4L..4L+3)
  int k0 = 2 * L, k1 = 2 * L + 1;
  int k0c = min(k0, L_N - 1), k1c = min(k1, L_N - 1);
  int y0 = max(ys[b * L_N + k0c], 0);
  int y1 = max(ys[b * L_N + k1c], 0);
  int y0m = (k0 > 0) ? max(ys[b * L_N + min(k0 - 1, L_N - 1)], 0) : -1;
  bool allow1 = (y0 != 0) && (y0 != y0m);
  bool allow3 = (y1 != 0) && (y1 != y0);
  int il = ilens[b];   // >= 250

  asm volatile("s_waitcnt vmcnt(0)" ::: "memory");   // all DMA landed

  const u32* P = (const u32*)sP;
  const float* PB = (const float*)sPBb;
  const float* CT = (const float*)sCTb;

  float a0 = 0.f, a1 = 0.f, a2 = 0.f, a3 = 0.f;
  {
    float pb0 = PB[0];
    u32 pk00 = P[0];
    float a1v = __uint_as_float((pk00 & 0xffffu) << 16);
    if (L == 0) { a0 = pb0; a1 = a1v; }
  }
  int accE = 0;

  // double-buffered 8-step blocks (pairs: stride-64-dword rows -> 2-way free;
  // PB: all-lane broadcast reads)
  u32 curP[8]; float curB[8];
#pragma unroll
  for (int u = 0; u < 8; ++u) {
    curP[u] = P[(1 + u) * 64 + L];
    curB[u] = PB[1 + u];
  }
  for (int t0 = 1; t0 < il; t0 += 8) {
    u32 nP[8]; float nB[8];
#pragma unroll
    for (int u = 0; u < 8; ++u) {
      int tn = min(t0 + 8 + u, T_N - 1);
      nP[u] = P[tn * 64 + L];
      nB[u] = PB[tn];
    }
#pragma unroll
    for (int u = 0; u < 8; ++u) {
      int t = t0 + u;
      float pk0 = __uint_as_float((curP[u] & 0xffffu) << 16);
      float pk1 = __uint_as_float(curP[u] & 0xffff0000u);
      float p3 = dpp_shr1(a3, 0.f);        // lane L <- a3 of lane L-1
      float p3m = allow1 ? p3 : 0.f;
      float a1m = allow3 ? a1 : 0.f;
      float n0 = (a0 + p3) * curB[u];          // blank s=4L
      float n1 = (a1 + a0 + p3m) * pk0;        // label s=4L+1
      float n2 = (a2 + a1) * curB[u];          // blank s=4L+2
      float n3 = (a3 + a2 + a1m) * pk1;        // label s=4L+3
      bool live = t < il;                      // wave-uniform freeze
      a0 = live ? n0 : a0; a1 = live ? n1 : a1;
      a2 = live ? n2 : a2; a3 = live ? n3 : a3;
    }
    // renormalize: scale so wave-max lands in [1,2); exact pow2 bookkeeping
    float m = fmaxf(fmaxf(a0, a1), fmaxf(a2, a3));
    m = wave_max(m, 0.f);                      // alphas >= 0
    u32 mb = (u32)__builtin_amdgcn_readlane(__float_as_int(m), 63);
    int ex = (int)((mb >> 23) & 0xffu);
    ex = (ex < 1) ? 1 : ex;
    float scale = __uint_as_float((u32)(254 - ex) << 23);   // 2^(127-ex)
    a0 *= scale; a1 *= scale; a2 *= scale; a3 *= scale;
    accE += ex - 127;
#pragma unroll
    for (int u = 0; u < 8; ++u) { curP[u] = nP[u]; curB[u] = nB[u]; }
  }

  // reclaim sum of c_t over t in [0, il)
  float cs = 0.f;
#pragma unroll
  for (int i = 0; i < 8; ++i) {
    int t = L + 64 * i;
    cs += (t < il) ? CT[t] : 0.f;
  }
  cs = wave_sum(cs);
  float csum = __int_as_float(__builtin_amdgcn_readlane(__float_as_int(cs), 63));

  int ol = olens[b];
  int s1 = 2 * ol, s2 = 2 * ol - 1;
  int j1 = s1 & 3, j2 = s2 & 3;
  float t1 = (j1 == 0) ? a0 : a2;
  float t2 = (j2 == 1) ? a1 : a3;
  float x1 = __shfl(t1, s1 >> 2);
  float x2 = __shfl(t2, s2 >> 2);
  float ll2 = __log2f(x1 + x2) + (float)accE + csum;   // log2 of likelihood
  if (L == 0) atomicAdd(out, -ll2 * LN2 * (1.0f / B_N));
}

extern "C" void kernel_launch(void* const* d_in, const int* in_sizes, int n_in,
                              void* d_out, int out_size, void* d_ws, size_t ws_size,
                              hipStream_t stream) {
  const float* hs    = (const float*)d_in[0];
  const float* W     = (const float*)d_in[1];
  const float* bias  = (const float*)d_in[2];
  const int*   ys    = (const int*)d_in[3];
  const int*   ilens = (const int*)d_in[4];
  const int*   olens = (const int*)d_in[5];
  char* ws = (char*)d_ws;
  u8*    Aq  = (u8*)(ws + OFF_A);
  u8*    Bq  = (u8*)(ws + OFF_B);
  u16*   C   = (u16*)(ws + OFF_C);
  u8*    lab = (u8*)(ws + OFF_LAB);
  float* out = (float*)d_out;

  castA<<<M_P * E_N / (256 * 4), 256, 0, stream>>>(hs, (u32*)Aq, out);
  castB<<<dim3(N_P / 32, E_N / 32), 256, 0, stream>>>(W, Bq);
  gemm_fp8<<<dim3(N_P / 128, M_P / 128), 256, 0, stream>>>(Aq, Bq, C);
  rowstat<<<B_N * T_N, 256, 0, stream>>>(C, bias, ys, lab);
  ctc_dp<<<B_N, 64, 0, stream>>>(lab, ys, ilens, olens, out);
}